// Round 1
// baseline (228.615 us; speedup 1.0000x reference)
//
#include <hip/hip_runtime.h>
#include <math.h>

// Converse2D (USRNet closed-form prox), s=2, B=4, C=64, H=W=128, K=5.
// out[b,c] = (1/4) * ifft2_128( X_bc ⊙ K_{c,pass} ), two polyphases per complex ifft.
// K_{c,pass} precomputed analytically from the 5x5 softmaxed PSF + lambda.

struct cx { float x, y; };
__device__ __forceinline__ cx cmul(cx a, cx b){ return cx{a.x*b.x - a.y*b.y, a.x*b.y + a.y*b.x}; }
__device__ __forceinline__ cx cadd(cx a, cx b){ return cx{a.x+b.x, a.y+b.y}; }
__device__ __forceinline__ cx csub(cx a, cx b){ return cx{a.x-b.x, a.y-b.y}; }
__device__ __forceinline__ cx cconj(cx a){ return cx{a.x, -a.y}; }
__device__ __forceinline__ cx cscale(cx a, float s){ return cx{a.x*s, a.y*s}; }

// Computes H_p(q,r) for the 4 output phases p=(pm,pn) at 128x128 base freq (q,r).
__device__ void compute_H(const float* __restrict__ wc, float lam, int q, int r, cx H[4])
{
    const float TWO_PI = 6.28318530717958647692f;
    cx er[5], eq[5];
    #pragma unroll
    for (int t = 0; t < 5; ++t) {
        float s_, c_;
        __sincosf(-TWO_PI * (float)(r * (t - 2)) * (1.0f/256.0f), &s_, &c_);
        er[t] = cx{c_, s_};
        __sincosf(-TWO_PI * (float)(q * (t - 2)) * (1.0f/256.0f), &s_, &c_);
        eq[t] = cx{c_, s_};
    }
    // P0[a] = sum_b w[a,b] er[b];  P1[a] = sum_b w[a,b] er[b] (-1)^b
    cx P0[5], P1[5];
    #pragma unroll
    for (int a = 0; a < 5; ++a) {
        cx p0{0.f,0.f}, p1{0.f,0.f};
        #pragma unroll
        for (int b = 0; b < 5; ++b) {
            cx t = cscale(er[b], wc[a*5 + b]);
            p0 = cadd(p0, t);
            p1 = (b & 1) ? csub(p1, t) : cadd(p1, t);
        }
        P0[a] = p0; P1[a] = p1;
    }
    // FB at the 4 aliases: F[i][k] = FB[q+128 i, r+128 k]
    cx F[2][2];
    F[0][0]=cx{0.f,0.f}; F[0][1]=cx{0.f,0.f}; F[1][0]=cx{0.f,0.f}; F[1][1]=cx{0.f,0.f};
    #pragma unroll
    for (int a = 0; a < 5; ++a) {
        cx t0 = cmul(eq[a], P0[a]);
        cx t1 = cmul(eq[a], P1[a]);
        F[0][0] = cadd(F[0][0], t0); F[0][1] = cadd(F[0][1], t1);
        if (a & 1) { F[1][0] = csub(F[1][0], t0); F[1][1] = csub(F[1][1], t1); }
        else       { F[1][0] = cadd(F[1][0], t0); F[1][1] = cadd(F[1][1], t1); }
    }
    float sq, cq, sr, cr;
    __sincosf(-TWO_PI * (float)q * (1.0f/256.0f), &sq, &cq);
    __sincosf(-TWO_PI * (float)r * (1.0f/256.0f), &sr, &cr);
    // Du_i = 1 + (-1)^i e^{-2pi i q/256}, Dv_k likewise
    cx Du[2] = { cx{1.f+cq,  sq}, cx{1.f-cq, -sq} };
    cx Dv[2] = { cx{1.f+cr,  sr}, cx{1.f-cr, -sr} };
    cx R[2][2];
    float invW = 0.f;
    cx M{0.f,0.f};
    #pragma unroll
    for (int i = 0; i < 2; ++i)
      #pragma unroll
      for (int k = 0; k < 2; ++k) {
        cx fb = F[i][k];
        cx Rik = cadd(cconj(fb), cscale(cmul(Du[i], Dv[k]), lam));
        R[i][k] = Rik;
        invW += 0.25f * (fb.x*fb.x + fb.y*fb.y);
        M = cadd(M, cscale(cmul(fb, Rik), 0.25f));
      }
    cx V = cscale(M, 1.0f / (invW + lam));
    float inv_lam = 1.0f / lam;
    cx G[2][2];
    #pragma unroll
    for (int i = 0; i < 2; ++i)
      #pragma unroll
      for (int k = 0; k < 2; ++k)
        G[i][k] = cscale(csub(R[i][k], cmul(cconj(F[i][k]), V)), inv_lam);

    cx G00 = G[0][0], G01 = G[0][1], G10 = G[1][0], G11 = G[1][1];
    cx Gh00 = cadd(cadd(G00,G01), cadd(G10,G11));     // (+,+,+,+)
    cx Gh01 = cadd(csub(G00,G01), csub(G10,G11));     // (-1)^k
    cx Gh10 = csub(cadd(G00,G01), cadd(G10,G11));     // (-1)^i
    cx Gh11 = csub(csub(G00,G01), csub(G10,G11));     // (-1)^{i+k}
    cx phq = cx{cq, -sq};   // e^{+2pi i q/256}
    cx phr = cx{cr, -sr};   // e^{+2pi i r/256}
    H[0] = Gh00;
    H[1] = cmul(Gh01, phr);
    H[2] = cmul(Gh10, phq);
    H[3] = cmul(Gh11, cmul(phq, phr));
}

__global__ __launch_bounds__(256)
void precompute_K(const float* __restrict__ weight, const float* __restrict__ lam_ptr,
                  float2* __restrict__ KA, float2* __restrict__ KB)
{
    int gid = blockIdx.x * 256 + threadIdx.x;   // 64 * 16384 threads
    int c = gid >> 14;
    int n = gid & 16383;
    int q = n >> 7, r = n & 127;
    float lam = lam_ptr[0];
    const float* wc = weight + c * 25;

    cx H[4], Hm[4];
    compute_H(wc, lam, q, r, H);
    int qm = (128 - q) & 127, rm = (128 - r) & 127;
    compute_H(wc, lam, qm, rm, Hm);

    // Hermitianize: Ht_p(q,r) = (H_p(q,r) + conj(H_p(-q,-r)))/2, fold 1/(4*128*128)
    const float scale = 0.5f * (1.0f / 65536.0f);
    cx Ht[4];
    #pragma unroll
    for (int p = 0; p < 4; ++p)
        Ht[p] = cx{ (H[p].x + Hm[p].x) * scale, (H[p].y - Hm[p].y) * scale };

    // Pack: KA = Ht(0,0) + i Ht(0,1)  (even rows);  KB = Ht(1,0) + i Ht(1,1) (odd rows)
    float2 kA = make_float2(Ht[0].x - Ht[1].y, Ht[0].y + Ht[1].x);
    float2 kB = make_float2(Ht[2].x - Ht[3].y, Ht[2].y + Ht[3].x);

    // store at 2D bit-reversed position (matches DIF output order)
    int qb = (int)(__brev((unsigned)q) >> 25);
    int rb = (int)(__brev((unsigned)r) >> 25);
    int idx = (c << 14) + (qb << 7) + rb;
    KA[idx] = kA;
    KB[idx] = kB;
}

#define ST 129   // padded LDS row stride (floats): +1 keeps all passes conflict-free

__global__ __launch_bounds__(1024)
void converse_main(const float* __restrict__ x, const float* __restrict__ bias,
                   const float2* __restrict__ KA, const float2* __restrict__ KB,
                   float* __restrict__ out)
{
    __shared__ float SR[128 * ST];
    __shared__ float SI[128 * ST];
    __shared__ float TWR[64];
    __shared__ float TWI[64];

    const int tid  = threadIdx.x;
    const int blk  = blockIdx.x;      // [0, 512)
    const int pass = blk & 1;         // 0: even output rows, 1: odd output rows
    const int bc   = blk >> 1;        // b*64 + c
    const int c    = bc & 63;

    if (tid < 64) {
        float s_, c_;
        __sincosf(-6.28318530717958647692f * (float)tid * (1.0f/128.0f), &s_, &c_);
        TWR[tid] = c_; TWI[tid] = s_;
    }

    // ---- load x[b,c] (128x128 real) ----
    const float* xp = x + (size_t)bc * 16384;
    #pragma unroll
    for (int it = 0; it < 16; ++it) {
        int n = it * 1024 + tid;
        int rr = n >> 7, cc = n & 127;
        SR[rr * ST + cc] = xp[n];
        SI[rr * ST + cc] = 0.0f;
    }
    __syncthreads();

    // ---- forward DIF, row pass (transform along n) ----
    for (int s = 0; s < 7; ++s) {
        int h = 64 >> s;
        #pragma unroll
        for (int it = 0; it < 8; ++it) {
            int gid  = it * 1024 + tid;
            int line = gid & 127;          // row index (varies across lanes)
            int j    = gid >> 7;           // butterfly id within line [0,64)
            int jj   = j & (h - 1);
            int i1   = ((j >> (6 - s)) << (7 - s)) + jj;
            int a1   = line * ST + i1;
            int a2   = a1 + h;
            float ur = SR[a1], ui = SI[a1], vr = SR[a2], vi = SI[a2];
            float wr_ = TWR[jj << s], wi_ = TWI[jj << s];
            SR[a1] = ur + vr; SI[a1] = ui + vi;
            float dr = ur - vr, di = ui - vi;
            SR[a2] = dr * wr_ - di * wi_;
            SI[a2] = dr * wi_ + di * wr_;
        }
        __syncthreads();
    }
    // ---- forward DIF, column pass (transform along m) ----
    for (int s = 0; s < 7; ++s) {
        int h = 64 >> s;
        #pragma unroll
        for (int it = 0; it < 8; ++it) {
            int gid  = it * 1024 + tid;
            int line = gid & 127;          // column index
            int j    = gid >> 7;
            int jj   = j & (h - 1);
            int i1   = ((j >> (6 - s)) << (7 - s)) + jj;
            int a1   = i1 * ST + line;
            int a2   = a1 + h * ST;
            float ur = SR[a1], ui = SI[a1], vr = SR[a2], vi = SI[a2];
            float wr_ = TWR[jj << s], wi_ = TWI[jj << s];
            SR[a1] = ur + vr; SI[a1] = ui + vi;
            float dr = ur - vr, di = ui - vi;
            SR[a2] = dr * wr_ - di * wi_;
            SI[a2] = dr * wi_ + di * wr_;
        }
        __syncthreads();
    }

    // ---- multiply by K (both sides stored in 2D bit-reversed order) ----
    {
        const float2* Kp = (pass == 0 ? KA : KB) + (size_t)c * 16384;
        #pragma unroll
        for (int it = 0; it < 16; ++it) {
            int n = it * 1024 + tid;
            int qq = n >> 7, rr = n & 127;
            float2 k = Kp[n];
            int a = qq * ST + rr;
            float xr = SR[a], xi = SI[a];
            SR[a] = xr * k.x - xi * k.y;
            SI[a] = xr * k.y + xi * k.x;
        }
    }
    __syncthreads();

    // ---- inverse DIT, column pass (along m), e^{+i} twiddles, unscaled ----
    for (int s = 0; s < 7; ++s) {
        int h = 1 << s;
        #pragma unroll
        for (int it = 0; it < 8; ++it) {
            int gid  = it * 1024 + tid;
            int line = gid & 127;          // column index
            int j    = gid >> 7;
            int jj   = j & (h - 1);
            int i1   = ((j >> s) << (s + 1)) + jj;
            int a1   = i1 * ST + line;
            int a2   = a1 + h * ST;
            float ur = SR[a1], ui = SI[a1], vr = SR[a2], vi = SI[a2];
            float wr_ = TWR[jj << (6 - s)], wi_ = -TWI[jj << (6 - s)];
            float tr = vr * wr_ - vi * wi_;
            float ti = vr * wi_ + vi * wr_;
            SR[a1] = ur + tr; SI[a1] = ui + ti;
            SR[a2] = ur - tr; SI[a2] = ui - ti;
        }
        __syncthreads();
    }
    // ---- inverse DIT, row pass (along n) ----
    for (int s = 0; s < 7; ++s) {
        int h = 1 << s;
        #pragma unroll
        for (int it = 0; it < 8; ++it) {
            int gid  = it * 1024 + tid;
            int line = gid & 127;          // row index
            int j    = gid >> 7;
            int jj   = j & (h - 1);
            int i1   = ((j >> s) << (s + 1)) + jj;
            int a1   = line * ST + i1;
            int a2   = a1 + h;
            float ur = SR[a1], ui = SI[a1], vr = SR[a2], vi = SI[a2];
            float wr_ = TWR[jj << (6 - s)], wi_ = -TWI[jj << (6 - s)];
            float tr = vr * wr_ - vi * wi_;
            float ti = vr * wi_ + vi * wr_;
            SR[a1] = ur + tr; SI[a1] = ui + ti;
            SR[a2] = ur - tr; SI[a2] = ui - ti;
        }
        __syncthreads();
    }

    // ---- store: Re -> col even, Im -> col odd; row = 2m'+pass ----
    const float bv = bias[c];
    float* op = out + (size_t)bc * 65536;
    #pragma unroll
    for (int it = 0; it < 16; ++it) {
        int n = it * 1024 + tid;
        int m = n >> 7, nn = n & 127;
        int a = m * ST + nn;
        float2 v = make_float2(SR[a] + bv, SI[a] + bv);
        *(float2*)(op + (size_t)(2 * m + pass) * 256 + 2 * nn) = v;
    }
}

extern "C" void kernel_launch(void* const* d_in, const int* in_sizes, int n_in,
                              void* d_out, int out_size, void* d_ws, size_t ws_size,
                              hipStream_t stream)
{
    const float* x      = (const float*)d_in[0];   // [4,64,128,128]
    const float* weight = (const float*)d_in[1];   // [1,64,5,5]
    const float* bias   = (const float*)d_in[2];   // [1,64,1,1]
    const float* lam    = (const float*)d_in[3];   // [1,1,1,1]
    float* out = (float*)d_out;                    // [4,64,256,256]

    float2* KA = (float2*)d_ws;                    // 64*16384 float2 = 16 MB
    float2* KB = KA + (size_t)64 * 16384;          // + 16 MB

    hipLaunchKernelGGL(precompute_K, dim3(64 * 16384 / 256), dim3(256), 0, stream,
                       weight, lam, KA, KB);
    hipLaunchKernelGGL(converse_main, dim3(512), dim3(1024), 0, stream,
                       x, bias, KA, KB, out);
}

// Round 2
// 158.530 us; speedup vs baseline: 1.4421x; 1.4421x over previous
//
#include <hip/hip_runtime.h>
#include <math.h>

// Converse2D (USRNet closed-form prox), s=2, B=4, C=64, H=W=128, K=5.
// Per (b,c): 1 fwd 128x128 FFT, then two {K-mult + inv FFT} passes packing the
// 4 output polyphases. Fused radix-2 stage pairs (radix-4 traffic), float2 LDS.

struct cx { float x, y; };
__device__ __forceinline__ cx cmul(cx a, cx b){ return cx{a.x*b.x - a.y*b.y, a.x*b.y + a.y*b.x}; }
__device__ __forceinline__ cx cadd(cx a, cx b){ return cx{a.x+b.x, a.y+b.y}; }
__device__ __forceinline__ cx csub(cx a, cx b){ return cx{a.x-b.x, a.y-b.y}; }
__device__ __forceinline__ cx cconj(cx a){ return cx{a.x, -a.y}; }
__device__ __forceinline__ cx cscale(cx a, float s){ return cx{a.x*s, a.y*s}; }

__device__ __forceinline__ float2 cmulf(float2 a, float2 b){
    return make_float2(a.x*b.x - a.y*b.y, a.x*b.y + a.y*b.x);
}
__device__ __forceinline__ float2 cmulcf(float2 a, float2 b){ // a * conj(b)
    return make_float2(a.x*b.x + a.y*b.y, a.y*b.x - a.x*b.y);
}
__device__ __forceinline__ float2 caddf(float2 a, float2 b){ return make_float2(a.x+b.x, a.y+b.y); }
__device__ __forceinline__ float2 csubf(float2 a, float2 b){ return make_float2(a.x-b.x, a.y-b.y); }

// H_p(q,r) for the 4 output phases, table-based twiddles.
// TAB[k] = e^{-2*pi*i*k/256}
__device__ __forceinline__ void compute_H_tab(const float* __restrict__ wc, float lam,
                                              int q, int r, const float2* __restrict__ TAB,
                                              cx H[4])
{
    cx er[5], eq[5];
    #pragma unroll
    for (int t = 0; t < 5; ++t) {
        float2 a = TAB[(r * (t - 2)) & 255];
        er[t] = cx{a.x, a.y};
        float2 b = TAB[(q * (t - 2)) & 255];
        eq[t] = cx{b.x, b.y};
    }
    cx P0[5], P1[5];
    #pragma unroll
    for (int a = 0; a < 5; ++a) {
        cx p0{0.f,0.f}, p1{0.f,0.f};
        #pragma unroll
        for (int b = 0; b < 5; ++b) {
            cx t = cscale(er[b], wc[a*5 + b]);
            p0 = cadd(p0, t);
            p1 = (b & 1) ? csub(p1, t) : cadd(p1, t);
        }
        P0[a] = p0; P1[a] = p1;
    }
    cx F[2][2];
    F[0][0]=cx{0.f,0.f}; F[0][1]=cx{0.f,0.f}; F[1][0]=cx{0.f,0.f}; F[1][1]=cx{0.f,0.f};
    #pragma unroll
    for (int a = 0; a < 5; ++a) {
        cx t0 = cmul(eq[a], P0[a]);
        cx t1 = cmul(eq[a], P1[a]);
        F[0][0] = cadd(F[0][0], t0); F[0][1] = cadd(F[0][1], t1);
        if (a & 1) { F[1][0] = csub(F[1][0], t0); F[1][1] = csub(F[1][1], t1); }
        else       { F[1][0] = cadd(F[1][0], t0); F[1][1] = cadd(F[1][1], t1); }
    }
    float cq = TAB[q].x, sq = TAB[q].y;   // (cos, -sin) of 2*pi*q/256
    float cr = TAB[r].x, sr = TAB[r].y;
    cx Du[2] = { cx{1.f+cq,  sq}, cx{1.f-cq, -sq} };
    cx Dv[2] = { cx{1.f+cr,  sr}, cx{1.f-cr, -sr} };
    cx R[2][2];
    float invW = 0.f;
    cx M{0.f,0.f};
    #pragma unroll
    for (int i = 0; i < 2; ++i)
      #pragma unroll
      for (int k = 0; k < 2; ++k) {
        cx fb = F[i][k];
        cx Rik = cadd(cconj(fb), cscale(cmul(Du[i], Dv[k]), lam));
        R[i][k] = Rik;
        invW += 0.25f * (fb.x*fb.x + fb.y*fb.y);
        M = cadd(M, cscale(cmul(fb, Rik), 0.25f));
      }
    cx V = cscale(M, 1.0f / (invW + lam));
    float inv_lam = 1.0f / lam;
    cx G[2][2];
    #pragma unroll
    for (int i = 0; i < 2; ++i)
      #pragma unroll
      for (int k = 0; k < 2; ++k)
        G[i][k] = cscale(csub(R[i][k], cmul(cconj(F[i][k]), V)), inv_lam);

    cx G00 = G[0][0], G01 = G[0][1], G10 = G[1][0], G11 = G[1][1];
    cx Gh00 = cadd(cadd(G00,G01), cadd(G10,G11));
    cx Gh01 = cadd(csub(G00,G01), csub(G10,G11));
    cx Gh10 = csub(cadd(G00,G01), cadd(G10,G11));
    cx Gh11 = csub(csub(G00,G01), csub(G10,G11));
    cx phq = cx{cq, -sq};
    cx phr = cx{cr, -sr};
    H[0] = Gh00;
    H[1] = cmul(Gh01, phr);
    H[2] = cmul(Gh10, phq);
    H[3] = cmul(Gh11, cmul(phq, phr));
}

__global__ __launch_bounds__(256)
void precompute_K(const float* __restrict__ weight, const float* __restrict__ lam_ptr,
                  float2* __restrict__ KA, float2* __restrict__ KB)
{
    __shared__ float2 TAB[256];
    __shared__ float WC[25];
    const int tid = threadIdx.x;
    {
        float s_, c_;
        __sincosf(-6.28318530717958647692f * (float)tid * (1.0f/256.0f), &s_, &c_);
        TAB[tid] = make_float2(c_, s_);
    }
    const int c = blockIdx.x >> 3;           // 512 blocks: 8 per channel
    if (tid < 25) WC[tid] = weight[c*25 + tid];
    __syncthreads();
    const float lam = lam_ptr[0];
    const int nbase = (blockIdx.x & 7) * 2048;
    const float scale = 1.0f / 65536.0f;     // ifft 1/(128*128) and 1/4 polyphase mean

    #pragma unroll 1
    for (int k = 0; k < 8; ++k) {
        int n = nbase + k*256 + tid;
        int q = n >> 7, r = n & 127;
        cx H[4];
        compute_H_tab(WC, lam, q, r, TAB, H);
        // H is exactly Hermitian on the 128-grid (proved: every factor conjugates
        // under (q,r)->(-q,-r)), so no symmetrization needed.
        float2 kAv = make_float2((H[0].x - H[1].y)*scale, (H[0].y + H[1].x)*scale);
        float2 kBv = make_float2((H[2].x - H[3].y)*scale, (H[2].y + H[3].x)*scale);
        int qb = (int)(__brev((unsigned)q) >> 25);
        int rb = (int)(__brev((unsigned)r) >> 25);
        int idx = (c << 14) + (qb << 7) + rb;
        KA[idx] = kAv;
        KB[idx] = kBv;
    }
}

#define ST2 129   // float2 stride: odd -> both row & col passes at bank-bandwidth minimum

template<int AXIS> __device__ __forceinline__ int laddr(int line, int i){
    return AXIS ? (i*ST2 + line) : (line*ST2 + i);
}

// Forward DIF, fused stages (S, S+1). S in {0,2,4}. 4096 quartets, 4/thread.
template<int AXIS, int S>
__device__ __forceinline__ void fwd_pair(float2* Sm, const float2* TW, int tid)
{
    const int h  = 64 >> S;
    const int hh = 32 >> S;
    #pragma unroll
    for (int it = 0; it < 4; ++it) {
        int qid  = it*1024 + tid;
        int line = qid & 127;
        int t    = qid >> 7;
        int blk  = t >> (5 - S);
        int j    = t & (hh - 1);
        int i0   = (blk << (7 - S)) + j;
        int a0 = laddr<AXIS>(line, i0);
        int a1 = laddr<AXIS>(line, i0 + hh);
        int a2 = laddr<AXIS>(line, i0 + h);
        int a3 = laddr<AXIS>(line, i0 + h + hh);
        float2 e0 = Sm[a0], e1 = Sm[a1], e2 = Sm[a2], e3 = Sm[a3];
        float2 w0 = TW[j << S], w1 = TW[(j << S) + 32], w2 = TW[j << (S + 1)];
        float2 u0 = caddf(e0, e2), d0 = cmulf(csubf(e0, e2), w0);
        float2 u1 = caddf(e1, e3), d1 = cmulf(csubf(e1, e3), w1);
        Sm[a0] = caddf(u0, u1);
        Sm[a1] = cmulf(csubf(u0, u1), w2);
        Sm[a2] = caddf(d0, d1);
        Sm[a3] = cmulf(csubf(d0, d1), w2);
    }
}

// Inverse DIT, fused stages (S, S+1). S in {0..5 odd/even as called}. conj twiddles.
template<int AXIS, int S>
__device__ __forceinline__ void inv_pair(float2* Sm, const float2* TW, int tid)
{
    const int h = 1 << S;
    #pragma unroll
    for (int it = 0; it < 4; ++it) {
        int qid  = it*1024 + tid;
        int line = qid & 127;
        int t    = qid >> 7;
        int blk  = t >> S;
        int j    = t & (h - 1);
        int base = (blk << (S + 2)) + j;
        int a0 = laddr<AXIS>(line, base);
        int a1 = laddr<AXIS>(line, base + h);
        int a2 = laddr<AXIS>(line, base + 2*h);
        int a3 = laddr<AXIS>(line, base + 3*h);
        float2 e0 = Sm[a0], e1 = Sm[a1], e2 = Sm[a2], e3 = Sm[a3];
        float2 cw0 = TW[j << (6 - S)];
        float2 cw1 = TW[j << (5 - S)];
        float2 cw2 = TW[(j << (5 - S)) + 32];
        float2 t1 = cmulcf(e1, cw0);
        float2 A0 = caddf(e0, t1), A1 = csubf(e0, t1);
        float2 t2 = cmulcf(e3, cw0);
        float2 A2 = caddf(e2, t2), A3 = csubf(e2, t2);
        float2 u = cmulcf(A2, cw1);
        Sm[a0] = caddf(A0, u);
        Sm[a2] = csubf(A0, u);
        float2 v = cmulcf(A3, cw2);
        Sm[a1] = caddf(A1, v);
        Sm[a3] = csubf(A1, v);
    }
}

__global__ __launch_bounds__(1024)
void converse_main(const float* __restrict__ x, const float* __restrict__ bias,
                   const float2* __restrict__ KA, const float2* __restrict__ KB,
                   float* __restrict__ out)
{
    __shared__ float2 S[128 * ST2];
    __shared__ float2 TW[64];

    const int tid = threadIdx.x;
    const int bc  = blockIdx.x;       // [0,256) = b*64 + c
    const int c   = bc & 63;

    if (tid < 64) {
        float s_, c_;
        __sincosf(-6.28318530717958647692f * (float)tid * (1.0f/128.0f), &s_, &c_);
        TW[tid] = make_float2(c_, s_);
    }

    // ---- load x[b,c] as {x, 0} (contiguous float2 writes, conflict-free) ----
    const float* xp = x + (size_t)bc * 16384;
    #pragma unroll
    for (int it = 0; it < 16; ++it) {
        int n = it * 1024 + tid;
        S[(n >> 7) * ST2 + (n & 127)] = make_float2(xp[n], 0.0f);
    }
    __syncthreads();

    // ---- forward rows (along n): fused (0,1),(2,3),(4,5), single 6 ----
    fwd_pair<0,0>(S, TW, tid); __syncthreads();
    fwd_pair<0,2>(S, TW, tid); __syncthreads();
    fwd_pair<0,4>(S, TW, tid); __syncthreads();
    #pragma unroll
    for (int it = 0; it < 8; ++it) {     // stage 6: pairs (2k,2k+1), twiddle 1
        int g = it*1024 + tid;
        int line = g & 127, k = g >> 7;
        int a = line*ST2 + 2*k;
        float2 u = S[a], v = S[a+1];
        S[a]   = caddf(u, v);
        S[a+1] = csubf(u, v);
    }
    __syncthreads();

    // ---- forward cols (along m): fused (0,1),(2,3),(4,5) ----
    fwd_pair<1,0>(S, TW, tid); __syncthreads();
    fwd_pair<1,2>(S, TW, tid); __syncthreads();
    fwd_pair<1,4>(S, TW, tid); __syncthreads();

    // ---- forward col stage 6 into registers (spectrum kept for both passes) ----
    float2 sA[8], sB[8];
    #pragma unroll
    for (int it = 0; it < 8; ++it) {
        int g = it*1024 + tid;
        int nn = g & 127, j = g >> 7;
        int a = (2*j)*ST2 + nn;
        float2 u = S[a], v = S[a + ST2];
        sA[it] = caddf(u, v);
        sB[it] = csubf(u, v);
    }
    // no barrier needed: each thread re-writes only its own addresses in the mult

    const float bv = bias[c];
    float* op = out + (size_t)bc * 65536;

    #pragma unroll 1
    for (int pass = 0; pass < 2; ++pass) {
        // ---- K-mult (from regs) fused with inverse col stage 0 (h=1, w=1) ----
        const float2* Kp = (pass ? KB : KA) + (size_t)c * 16384;
        #pragma unroll
        for (int it = 0; it < 8; ++it) {
            int g = it*1024 + tid;
            int nn = g & 127, j = g >> 7;
            float2 kA = Kp[(j << 8) + nn];
            float2 kB = Kp[(j << 8) + 128 + nn];
            float2 w0 = cmulf(sA[it], kA);
            float2 w1 = cmulf(sB[it], kB);
            int a = (2*j)*ST2 + nn;
            S[a]       = caddf(w0, w1);
            S[a + ST2] = csubf(w0, w1);
        }
        __syncthreads();

        // ---- inverse cols: fused (1,2),(3,4),(5,6) ----
        inv_pair<1,1>(S, TW, tid); __syncthreads();
        inv_pair<1,3>(S, TW, tid); __syncthreads();
        inv_pair<1,5>(S, TW, tid); __syncthreads();

        // ---- inverse rows: fused (0,1),(2,3),(4,5) ----
        inv_pair<0,0>(S, TW, tid); __syncthreads();
        inv_pair<0,2>(S, TW, tid); __syncthreads();
        inv_pair<0,4>(S, TW, tid); __syncthreads();

        // ---- inverse row stage 6 fused with store (Re->even col, Im->odd col) ----
        #pragma unroll
        for (int it = 0; it < 8; ++it) {
            int g = it*1024 + tid;
            int j = g & 63, m = g >> 6;
            int a = m*ST2 + j;
            float2 u = S[a], v = S[a + 64];
            float2 t = cmulcf(v, TW[j]);
            float2 o0 = caddf(u, t);
            float2 o1 = csubf(u, t);
            size_t ro = (size_t)(2*m + pass) * 256;
            *(float2*)(op + ro + 2*j)       = make_float2(o0.x + bv, o0.y + bv);
            *(float2*)(op + ro + 2*j + 128) = make_float2(o1.x + bv, o1.y + bv);
        }
        __syncthreads();   // protect S from next pass's mult writes
    }
}

extern "C" void kernel_launch(void* const* d_in, const int* in_sizes, int n_in,
                              void* d_out, int out_size, void* d_ws, size_t ws_size,
                              hipStream_t stream)
{
    const float* x      = (const float*)d_in[0];   // [4,64,128,128]
    const float* weight = (const float*)d_in[1];   // [1,64,5,5]
    const float* bias   = (const float*)d_in[2];   // [1,64,1,1]
    const float* lam    = (const float*)d_in[3];   // [1,1,1,1]
    float* out = (float*)d_out;                    // [4,64,256,256]

    float2* KA = (float2*)d_ws;                    // 16 MB
    float2* KB = KA + (size_t)64 * 16384;          // 16 MB

    hipLaunchKernelGGL(precompute_K, dim3(512), dim3(256), 0, stream,
                       weight, lam, KA, KB);
    hipLaunchKernelGGL(converse_main, dim3(256), dim3(1024), 0, stream,
                       x, bias, KA, KB, out);
}